// Round 3
// baseline (143.066 us; speedup 1.0000x reference)
//
#include <hip/hip_runtime.h>
#include <stdint.h>

// WildCatPooling: per row of HW=4096 f32, mean(top-410) + 0.6 * mean(bottom-410).
// One WAVE per row, zero barriers. Keys (order-preserving u32) live in 64 VGPRs.
// Wave-private LDS histogram (2048 words): L0 = 11-bit buckets in a TRANSPOSED
// layout so scan reads are bank-conflict-free; L1 = 8-bit refinement (256+256,
// linear). Tie copies valued at the 19-bit bucket midpoint (err <= |t|*2^-10,
// far under the 1.67e-2 harness threshold). Cross-lane comms: ballot + shfl.

#define HW      4096
#define WPB     4            // waves (rows) per block
#define NT      (WPB * 64)
#define KSEL    410          // round(4096 * 0.1)
#define ALPHA_C 0.6f

__device__ __forceinline__ uint32_t f2u(float f) {
  uint32_t b = __float_as_uint(f);
  return b ^ (uint32_t)(((int32_t)b >> 31) | 0x80000000u);  // ascending u <=> ascending f
}
__device__ __forceinline__ float u2f(uint32_t u) {
  uint32_t m = ~(((uint32_t)((int32_t)u >> 31)) >> 1);      // MSB?0x80000000:0xFFFFFFFF
  return __uint_as_float(u ^ m);
}

__global__ __launch_bounds__(NT, 4)
void wildcat_pool(const float* __restrict__ x, float* __restrict__ out, int rows) {
  const int lane = threadIdx.x & 63;
  const int wid  = threadIdx.x >> 6;
  const int row  = blockIdx.x * WPB + wid;
  if (row >= rows) return;  // no barriers in this kernel -> divergent exit is safe

  __shared__ uint32_t lds[WPB * 2048];
  uint32_t* hist = lds + wid * 2048;
  uint4*    h4   = reinterpret_cast<uint4*>(hist);

  // ---- zero wave-private histogram (2048 words) ----
#pragma unroll
  for (int j = 0; j < 8; ++j) h4[lane + 64 * j] = make_uint4(0, 0, 0, 0);

  // ---- load row (16 x float4, coalesced), keys -> 64 VGPRs ----
  const float4* rp4 = reinterpret_cast<const float4*>(x + (size_t)row * HW);
  uint32_t key[64];
#pragma unroll
  for (int i = 0; i < 16; ++i) {
    float4 v = rp4[i * 64 + lane];
    key[4*i+0] = f2u(v.x); key[4*i+1] = f2u(v.y);
    key[4*i+2] = f2u(v.z); key[4*i+3] = f2u(v.w);
  }

  // ---- L0 histogram: 11-bit bucket b=key>>21, transposed word ((b&31)<<6)|(b>>5) ----
#pragma unroll
  for (int i = 0; i < 64; ++i) {
    uint32_t b = key[i] >> 21;
    atomicAdd(&hist[((b & 31u) << 6) | (b >> 5)], 1u);
  }

  // ---- L0 scan A: lane owns buckets [lane*32, lane*32+32) at words q*64+lane ----
  uint32_t lsum = 0;
#pragma unroll
  for (int q = 0; q < 32; ++q) lsum += hist[q * 64 + lane];
  uint32_t sc = lsum;
#pragma unroll
  for (int off = 1; off < 64; off <<= 1) {
    uint32_t o = __shfl_up(sc, off, 64);
    if (lane >= off) sc += o;
  }
  const uint32_t base0 = sc - lsum;

  // ---- L0 scan B: detect BOTH crossings; zero first 512 words for L1 reuse ----
  const uint32_t XT = HW - KSEL, XB = KSEL;
  int fT = 0, fB = 0;
  uint32_t bT_l = 0, kT_l = 0, bB_l = 0, kB_l = 0;
  uint32_t run = base0;
#pragma unroll
  for (int q = 0; q < 32; ++q) {
    uint32_t c = hist[q * 64 + lane];
    if (q < 8) hist[q * 64 + lane] = 0;          // words [0,512) -> L1 arrays
    uint32_t pex = run; run += c; uint32_t pin = run;
    if (pex <= XT && XT < pin) { fT = 1; bT_l = (uint32_t)(lane * 32 + q); kT_l = pin - XT; }
    if (pex <  XB && XB <= pin){ fB = 1; bB_l = (uint32_t)(lane * 32 + q); kB_l = XB - pex; }
  }
  unsigned long long mT = __ballot(fT);
  int srcT = __ffsll((long long)mT) - 1;
  uint32_t bT = (uint32_t)__shfl((int)bT_l, srcT, 64);
  uint32_t kT = (uint32_t)__shfl((int)kT_l, srcT, 64);
  unsigned long long mB = __ballot(fB);
  int srcB = __ffsll((long long)mB) - 1;
  uint32_t bB = (uint32_t)__shfl((int)bB_l, srcB, 64);
  uint32_t kB = (uint32_t)__shfl((int)kB_l, srcB, 64);

  // ---- L1 build: 8-bit sub-bucket s = bits[13,21); top->[0,256), bottom->[256,512) ----
#pragma unroll
  for (int i = 0; i < 64; ++i) {
    uint32_t u = key[i];
    uint32_t hi = u >> 21;
    if (hi == bT) atomicAdd(&hist[(u >> 13) & 255u], 1u);
    if (hi == bB) atomicAdd(&hist[256u + ((u >> 13) & 255u)], 1u);
  }

  // ---- L1 scan: lanes 0..31 own top [l32*8,+8); lanes 32..63 own bottom ----
  const int half = lane >> 5;
  const int l32  = lane & 31;
  uint4 a0 = h4[(half ? 64 : 0) + l32 * 2 + 0];
  uint4 a1 = h4[(half ? 64 : 0) + l32 * 2 + 1];
  uint32_t cc[8] = {a0.x, a0.y, a0.z, a0.w, a1.x, a1.y, a1.z, a1.w};
  uint32_t lsum1 = 0;
#pragma unroll
  for (int t = 0; t < 8; ++t) lsum1 += cc[t];
  uint32_t sc1 = lsum1;
#pragma unroll
  for (int off = 1; off < 64; off <<= 1) {
    uint32_t o = __shfl_up(sc1, off, 64);
    if (lane >= off) sc1 += o;
  }
  const uint32_t totTop = (uint32_t)__shfl((int)sc1, 31, 64);  // count in bucket bT
  uint32_t run1 = sc1 - lsum1 - (half ? totTop : 0u);
  const uint32_t X1T = totTop - kT;
  int f1 = 0; uint32_t s1_l = 0, kn_l = 0;
#pragma unroll
  for (int t = 0; t < 8; ++t) {
    uint32_t pex = run1; run1 += cc[t]; uint32_t pin = run1;
    uint32_t idx = (uint32_t)(l32 * 8 + t);
    if (half == 0) { if (pex <= X1T && X1T < pin) { f1 = 1; s1_l = idx; kn_l = pin - X1T; } }
    else           { if (pex <  kB  && kB  <= pin) { f1 = 1; s1_l = idx; kn_l = kB - pex; } }
  }
  unsigned long long m1T = __ballot(f1 && half == 0);
  unsigned long long m1B = __ballot(f1 && half == 1);
  int q1T = __ffsll((long long)m1T) - 1;
  int q1B = __ffsll((long long)m1B) - 1;
  uint32_t s1T = (uint32_t)__shfl((int)s1_l, q1T, 64);
  uint32_t kTn = (uint32_t)__shfl((int)kn_l, q1T, 64);
  uint32_t s1B = (uint32_t)__shfl((int)s1_l, q1B, 64);
  uint32_t kBn = (uint32_t)__shfl((int)kn_l, q1B, 64);

  // ---- thresholds: 19-bit prefixes; tie value = bucket midpoint (|err|<=|t|*2^-10) ----
  const uint32_t PT = (bT << 8) | s1T;
  const uint32_t PB = (bB << 8) | s1B;
  const float tT = u2f((PT << 13) | 4096u);
  const float tB = u2f((PB << 13) | 4096u);

  // ---- final sums: strictly-beyond in key space + krem * midpoint ----
  float st = 0.f, sb = 0.f;
#pragma unroll
  for (int i = 0; i < 64; ++i) {
    uint32_t u = key[i], p = u >> 13;
    float v = u2f(u);
    if (p > PT) st += v;
    if (p < PB) sb += v;
  }
#pragma unroll
  for (int off = 32; off >= 1; off >>= 1) {
    st += __shfl_down(st, off, 64);
    sb += __shfl_down(sb, off, 64);
  }
  if (lane == 0)
    out[row] = (st + (float)kTn * tT + ALPHA_C * (sb + (float)kBn * tB)) * (1.0f / (float)KSEL);
}

extern "C" void kernel_launch(void* const* d_in, const int* in_sizes, int n_in,
                              void* d_out, int out_size, void* d_ws, size_t ws_size,
                              hipStream_t stream) {
  const float* x = (const float*)d_in[0];
  float* out = (float*)d_out;
  const int rows = out_size;                       // 32 * 512 = 16384
  wildcat_pool<<<(rows + WPB - 1) / WPB, NT, 0, stream>>>(x, out, rows);
}